// Round 1
// baseline (13685.625 us; speedup 1.0000x reference)
//
#include <hip/hip_runtime.h>
#include <math.h>

#define VOCAB  32000
#define EMBED  256
#define HIDDEN 512
#define BATCH  32
#define MAXLEN 128

#define VBLK  128
#define KTILE 64

// -------- workspace layout (bytes) --------
// 0        : h_buf[2][32][512] float   (131072 B)
// 131072   : c_buf[32][512]    float   ( 65536 B)
// 196608   : slots[128][32]    u64     ( 32768 B)  packed argmax (key<<32 | ~v)
#define WS_H_OFF 0
#define WS_C_OFF 131072
#define WS_S_OFF 196608
#define WS_BYTES 229376

__device__ __forceinline__ unsigned int f32_ordered_key(float f) {
    unsigned int b = __float_as_uint(f);
    return (b & 0x80000000u) ? ~b : (b | 0x80000000u);
}

// ---------------- Kernel A: gather + gates GEMM + LSTM cell ----------------
// grid 64 x 256 threads.  thread (b = tid&31, jl = tid>>5); j = blk*8 + jl.
__global__ __launch_bounds__(256) void lstm_step_kernel(
    const float* __restrict__ embed,
    const float* __restrict__ W_ih, const float* __restrict__ W_hh,
    const float* __restrict__ b_ih, const float* __restrict__ b_hh,
    const unsigned long long* __restrict__ slots,
    const float* __restrict__ h_prev, float* __restrict__ h_next,
    float* __restrict__ c_buf, int t)
{
    __shared__ float x_s[BATCH][EMBED + 1];   // pad -> conflict-free lane-per-b reads
    __shared__ float h_s[BATCH][HIDDEN + 1];
    __shared__ int   tok_s[BATCH];

    const int tid = threadIdx.x;
    if (tid < BATCH) {
        int tok = 0;
        if (t > 0) {
            unsigned long long s = slots[(size_t)(t - 1) * BATCH + tid];
            tok = (int)(~(unsigned int)(s & 0xFFFFFFFFull));
        }
        tok_s[tid] = tok;
    }
    __syncthreads();

    for (int idx = tid; idx < BATCH * EMBED; idx += 256) {
        int b = idx >> 8, e = idx & 255;
        x_s[b][e] = embed[(size_t)tok_s[b] * EMBED + e];
    }
    for (int idx = tid; idx < BATCH * HIDDEN; idx += 256) {
        int b = idx >> 9, k = idx & 511;
        h_s[b][k] = h_prev[(size_t)b * HIDDEN + k];
    }
    __syncthreads();

    const int b  = tid & 31;
    const int jl = tid >> 5;
    const int j  = blockIdx.x * 8 + jl;   // 0..511

    // gate order: i, f, g, o  (PyTorch LSTMCell)
    float A0 = b_ih[j]              + b_hh[j];
    float A1 = b_ih[HIDDEN + j]     + b_hh[HIDDEN + j];
    float A2 = b_ih[2 * HIDDEN + j] + b_hh[2 * HIDDEN + j];
    float A3 = b_ih[3 * HIDDEN + j] + b_hh[3 * HIDDEN + j];
    float B0 = 0.f, B1 = 0.f, B2 = 0.f, B3 = 0.f;

    const float4* wi0 = (const float4*)(W_ih + (size_t)j * EMBED);
    const float4* wi1 = (const float4*)(W_ih + (size_t)(HIDDEN + j) * EMBED);
    const float4* wi2 = (const float4*)(W_ih + (size_t)(2 * HIDDEN + j) * EMBED);
    const float4* wi3 = (const float4*)(W_ih + (size_t)(3 * HIDDEN + j) * EMBED);
    #pragma unroll 4
    for (int e4 = 0; e4 < EMBED / 4; ++e4) {
        float4 w0 = wi0[e4], w1 = wi1[e4], w2 = wi2[e4], w3 = wi3[e4];
        int e = e4 * 4;
        float x0 = x_s[b][e + 0], x1 = x_s[b][e + 1], x2 = x_s[b][e + 2], x3 = x_s[b][e + 3];
        A0 = fmaf(w0.x, x0, A0); B0 = fmaf(w0.y, x1, B0); A0 = fmaf(w0.z, x2, A0); B0 = fmaf(w0.w, x3, B0);
        A1 = fmaf(w1.x, x0, A1); B1 = fmaf(w1.y, x1, B1); A1 = fmaf(w1.z, x2, A1); B1 = fmaf(w1.w, x3, B1);
        A2 = fmaf(w2.x, x0, A2); B2 = fmaf(w2.y, x1, B2); A2 = fmaf(w2.z, x2, A2); B2 = fmaf(w2.w, x3, B2);
        A3 = fmaf(w3.x, x0, A3); B3 = fmaf(w3.y, x1, B3); A3 = fmaf(w3.z, x2, A3); B3 = fmaf(w3.w, x3, B3);
    }

    const float4* wh0 = (const float4*)(W_hh + (size_t)j * HIDDEN);
    const float4* wh1 = (const float4*)(W_hh + (size_t)(HIDDEN + j) * HIDDEN);
    const float4* wh2 = (const float4*)(W_hh + (size_t)(2 * HIDDEN + j) * HIDDEN);
    const float4* wh3 = (const float4*)(W_hh + (size_t)(3 * HIDDEN + j) * HIDDEN);
    #pragma unroll 4
    for (int k4 = 0; k4 < HIDDEN / 4; ++k4) {
        float4 w0 = wh0[k4], w1 = wh1[k4], w2 = wh2[k4], w3 = wh3[k4];
        int k = k4 * 4;
        float x0 = h_s[b][k + 0], x1 = h_s[b][k + 1], x2 = h_s[b][k + 2], x3 = h_s[b][k + 3];
        A0 = fmaf(w0.x, x0, A0); B0 = fmaf(w0.y, x1, B0); A0 = fmaf(w0.z, x2, A0); B0 = fmaf(w0.w, x3, B0);
        A1 = fmaf(w1.x, x0, A1); B1 = fmaf(w1.y, x1, B1); A1 = fmaf(w1.z, x2, A1); B1 = fmaf(w1.w, x3, B1);
        A2 = fmaf(w2.x, x0, A2); B2 = fmaf(w2.y, x1, B2); A2 = fmaf(w2.z, x2, A2); B2 = fmaf(w2.w, x3, B2);
        A3 = fmaf(w3.x, x0, A3); B3 = fmaf(w3.y, x1, B3); A3 = fmaf(w3.z, x2, A3); B3 = fmaf(w3.w, x3, B3);
    }

    float gi = A0 + B0, gf = A1 + B1, gg = A2 + B2, go = A3 + B3;
    float iv = 1.f / (1.f + expf(-gi));
    float fv = 1.f / (1.f + expf(-gf));
    float gv = tanhf(gg);
    float ov = 1.f / (1.f + expf(-go));

    const size_t off = (size_t)b * HIDDEN + j;
    float cn = fv * c_buf[off] + iv * gv;
    c_buf[off] = cn;
    h_next[off] = ov * tanhf(cn);
}

// ---------------- Kernel B: logits GEMM + store + argmax ----------------
// grid 250 x 256 threads.  block tile: 128 v x 32 b.
// thread (vq = tid&31, bq = tid>>5): v in {vbase+vq+32i}, b in {4bq..4bq+3}
__global__ __launch_bounds__(256) void logits_kernel(
    const float* __restrict__ W_fc, const float* __restrict__ b_fc,
    const float* __restrict__ h, float* __restrict__ out,
    unsigned long long* __restrict__ slots, int t)
{
    __shared__ float W_s[VBLK][KTILE + 1];   // pad 65: bank = (v + c) % 32, conflict-free
    __shared__ float h_s[BATCH][KTILE + 1];

    const int tid   = threadIdx.x;
    const int vbase = blockIdx.x * VBLK;
    const int vq    = tid & 31;
    const int bq    = tid >> 5;
    const int b0    = bq * 4;

    float acc[4][4] = {{0.f}};

    for (int kt = 0; kt < HIDDEN / KTILE; ++kt) {
        const int kb = kt * KTILE;
        __syncthreads();
        for (int idx = tid; idx < VBLK * KTILE; idx += 256) {
            int r = idx >> 6, cc = idx & 63;
            W_s[r][cc] = W_fc[(size_t)(vbase + r) * HIDDEN + kb + cc];
        }
        for (int idx = tid; idx < BATCH * KTILE; idx += 256) {
            int r = idx >> 6, cc = idx & 63;
            h_s[r][cc] = h[(size_t)r * HIDDEN + kb + cc];
        }
        __syncthreads();

        #pragma unroll 8
        for (int c = 0; c < KTILE; ++c) {
            float hv[4], wv[4];
            #pragma unroll
            for (int jj = 0; jj < 4; ++jj) hv[jj] = h_s[b0 + jj][c];
            #pragma unroll
            for (int i = 0; i < 4; ++i)  wv[i] = W_s[vq + 32 * i][c];
            #pragma unroll
            for (int i = 0; i < 4; ++i)
                #pragma unroll
                for (int jj = 0; jj < 4; ++jj)
                    acc[i][jj] = fmaf(wv[i], hv[jj], acc[i][jj]);
        }
    }

    // epilogue: bias, store logits, block/wave argmax, atomic merge
    float bfc[4];
    #pragma unroll
    for (int i = 0; i < 4; ++i) bfc[i] = b_fc[vbase + vq + 32 * i];

    unsigned long long best[4] = {0ull, 0ull, 0ull, 0ull};
    #pragma unroll
    for (int i = 0; i < 4; ++i) {
        const int v = vbase + vq + 32 * i;
        #pragma unroll
        for (int jj = 0; jj < 4; ++jj) {
            float val = acc[i][jj] + bfc[i];
            out[((size_t)(b0 + jj) * MAXLEN + t) * VOCAB + v] = val;
            unsigned long long enc =
                ((unsigned long long)f32_ordered_key(val) << 32) |
                (unsigned long long)(~(unsigned int)v);
            if (enc > best[jj]) best[jj] = enc;
        }
    }
    #pragma unroll
    for (int jj = 0; jj < 4; ++jj) {
        unsigned long long m = best[jj];
        #pragma unroll
        for (int s = 16; s >= 1; s >>= 1) {
            unsigned long long o = __shfl_xor(m, s, 64);  // stays inside 32-lane half
            if (o > m) m = o;
        }
        if (vq == 0)
            atomicMax(&slots[(size_t)t * BATCH + b0 + jj], m);
    }
}

extern "C" void kernel_launch(void* const* d_in, const int* in_sizes, int n_in,
                              void* d_out, int out_size, void* d_ws, size_t ws_size,
                              hipStream_t stream) {
    // inputs: text(int64, unused - only shape), embed, W_ih, W_hh, b_ih, b_hh, W_fc, b_fc
    const float* embed = (const float*)d_in[1];
    const float* W_ih  = (const float*)d_in[2];
    const float* W_hh  = (const float*)d_in[3];
    const float* b_ih  = (const float*)d_in[4];
    const float* b_hh  = (const float*)d_in[5];
    const float* W_fc  = (const float*)d_in[6];
    const float* b_fc  = (const float*)d_in[7];
    float* out = (float*)d_out;

    float* h_buf = (float*)((char*)d_ws + WS_H_OFF);       // 2 x 32 x 512
    float* c_buf = (float*)((char*)d_ws + WS_C_OFF);       // 32 x 512
    unsigned long long* slots = (unsigned long long*)((char*)d_ws + WS_S_OFF);

    // zero h[0], c, argmax slots (key 0 < any real logit key)
    hipMemsetAsync(d_ws, 0, WS_BYTES, stream);

    for (int t = 0; t < MAXLEN; ++t) {
        float* h_prev = h_buf + (size_t)(t & 1) * BATCH * HIDDEN;
        float* h_next = h_buf + (size_t)((t + 1) & 1) * BATCH * HIDDEN;
        lstm_step_kernel<<<64, 256, 0, stream>>>(
            embed, W_ih, W_hh, b_ih, b_hh, slots, h_prev, h_next, c_buf, t);
        logits_kernel<<<250, 256, 0, stream>>>(
            W_fc, b_fc, h_next, out, slots, t);
    }
}

// Round 2
// 8109.982 us; speedup vs baseline: 1.6875x; 1.6875x over previous
//
#include <hip/hip_runtime.h>
#include <hip/hip_bf16.h>
#include <math.h>

#define VOCAB  32000
#define EMBED  256
#define HIDDEN 512
#define BATCH  32
#define MAXLEN 128

typedef __attribute__((ext_vector_type(8))) short bf16x8;   // 8 bf16 = 4 VGPR
typedef __attribute__((ext_vector_type(4))) float f32x4;

// -------- workspace layout (bytes) --------
#define WS_H_OFF      0          // h_buf[2][32][512] f32   131072
#define WS_C_OFF      131072     // c_buf[32][512]    f32    65536
#define WS_S_OFF      196608     // slots[128][32]    u64    32768
#define WS_ZERO_BYTES 229376
#define WS_HHI_OFF    229376     // h_hi[32][512] bf16       32768
#define WS_HLO_OFF    262144     // h_lo[32][512] bf16       32768
#define WS_WHI_OFF    294912     // W_hi[32000][512] bf16 32768000
#define WS_WLO_OFF    33062912   // W_lo[32000][512] bf16 32768000
#define WS_REQUIRED   65830912ULL

__device__ __forceinline__ unsigned int f32_ordered_key(float f) {
    unsigned int b = __float_as_uint(f);
    return (b & 0x80000000u) ? ~b : (b | 0x80000000u);
}
__device__ __forceinline__ unsigned short f2bf(float x) {
    __hip_bfloat16 h = __float2bfloat16(x);
    return *reinterpret_cast<unsigned short*>(&h);
}
__device__ __forceinline__ float bf2f(unsigned short u) {
    __hip_bfloat16 h = *reinterpret_cast<__hip_bfloat16*>(&u);
    return __bfloat162float(h);
}

// ---------------- W_fc bf16 split precompute (once per launch) ----------------
__global__ __launch_bounds__(256) void split_w_kernel(
    const float* __restrict__ W, unsigned short* __restrict__ hi,
    unsigned short* __restrict__ lo, int n4)
{
    const int stride = gridDim.x * blockDim.x;
    for (int i = blockIdx.x * blockDim.x + threadIdx.x; i < n4; i += stride) {
        f32x4 w = ((const f32x4*)W)[i];
        ushort4 hv, lv;
        #pragma unroll
        for (int j = 0; j < 4; ++j) {
            float x = w[j];
            unsigned short hb = f2bf(x);
            ((unsigned short*)&hv)[j] = hb;
            ((unsigned short*)&lv)[j] = f2bf(x - bf2f(hb));
        }
        ((ushort4*)hi)[i] = hv;
        ((ushort4*)lo)[i] = lv;
    }
}

// ---------------- Kernel A: gather + gates GEMM + LSTM cell ----------------
// grid 64 x 256 threads.  thread (b = tid&31, jl = tid>>5); j = blk*8 + jl.
__global__ __launch_bounds__(256) void lstm_step_kernel(
    const float* __restrict__ embed,
    const float* __restrict__ W_ih, const float* __restrict__ W_hh,
    const float* __restrict__ b_ih, const float* __restrict__ b_hh,
    const unsigned long long* __restrict__ slots,
    const float* __restrict__ h_prev, float* __restrict__ h_next,
    float* __restrict__ c_buf,
    unsigned short* __restrict__ h_hi, unsigned short* __restrict__ h_lo, int t)
{
    __shared__ float x_s[BATCH][EMBED + 1];
    __shared__ float h_s[BATCH][HIDDEN + 1];
    __shared__ int   tok_s[BATCH];

    const int tid = threadIdx.x;
    if (tid < BATCH) {
        int tok = 0;
        if (t > 0) {
            unsigned long long s = slots[(size_t)(t - 1) * BATCH + tid];
            tok = (int)(~(unsigned int)(s & 0xFFFFFFFFull));
        }
        tok_s[tid] = tok;
    }
    __syncthreads();

    for (int idx = tid; idx < BATCH * EMBED; idx += 256) {
        int b = idx >> 8, e = idx & 255;
        x_s[b][e] = embed[(size_t)tok_s[b] * EMBED + e];
    }
    for (int idx = tid; idx < BATCH * HIDDEN; idx += 256) {
        int b = idx >> 9, k = idx & 511;
        h_s[b][k] = h_prev[(size_t)b * HIDDEN + k];
    }
    __syncthreads();

    const int b  = tid & 31;
    const int jl = tid >> 5;
    const int j  = blockIdx.x * 8 + jl;   // 0..511

    float A0 = b_ih[j]              + b_hh[j];
    float A1 = b_ih[HIDDEN + j]     + b_hh[HIDDEN + j];
    float A2 = b_ih[2 * HIDDEN + j] + b_hh[2 * HIDDEN + j];
    float A3 = b_ih[3 * HIDDEN + j] + b_hh[3 * HIDDEN + j];
    float B0 = 0.f, B1 = 0.f, B2 = 0.f, B3 = 0.f;

    const float4* wi0 = (const float4*)(W_ih + (size_t)j * EMBED);
    const float4* wi1 = (const float4*)(W_ih + (size_t)(HIDDEN + j) * EMBED);
    const float4* wi2 = (const float4*)(W_ih + (size_t)(2 * HIDDEN + j) * EMBED);
    const float4* wi3 = (const float4*)(W_ih + (size_t)(3 * HIDDEN + j) * EMBED);
    #pragma unroll 4
    for (int e4 = 0; e4 < EMBED / 4; ++e4) {
        float4 w0 = wi0[e4], w1 = wi1[e4], w2 = wi2[e4], w3 = wi3[e4];
        int e = e4 * 4;
        float x0 = x_s[b][e + 0], x1 = x_s[b][e + 1], x2 = x_s[b][e + 2], x3 = x_s[b][e + 3];
        A0 = fmaf(w0.x, x0, A0); B0 = fmaf(w0.y, x1, B0); A0 = fmaf(w0.z, x2, A0); B0 = fmaf(w0.w, x3, B0);
        A1 = fmaf(w1.x, x0, A1); B1 = fmaf(w1.y, x1, B1); A1 = fmaf(w1.z, x2, A1); B1 = fmaf(w1.w, x3, B1);
        A2 = fmaf(w2.x, x0, A2); B2 = fmaf(w2.y, x1, B2); A2 = fmaf(w2.z, x2, A2); B2 = fmaf(w2.w, x3, B2);
        A3 = fmaf(w3.x, x0, A3); B3 = fmaf(w3.y, x1, B3); A3 = fmaf(w3.z, x2, A3); B3 = fmaf(w3.w, x3, B3);
    }

    const float4* wh0 = (const float4*)(W_hh + (size_t)j * HIDDEN);
    const float4* wh1 = (const float4*)(W_hh + (size_t)(HIDDEN + j) * HIDDEN);
    const float4* wh2 = (const float4*)(W_hh + (size_t)(2 * HIDDEN + j) * HIDDEN);
    const float4* wh3 = (const float4*)(W_hh + (size_t)(3 * HIDDEN + j) * HIDDEN);
    #pragma unroll 4
    for (int k4 = 0; k4 < HIDDEN / 4; ++k4) {
        float4 w0 = wh0[k4], w1 = wh1[k4], w2 = wh2[k4], w3 = wh3[k4];
        int k = k4 * 4;
        float x0 = h_s[b][k + 0], x1 = h_s[b][k + 1], x2 = h_s[b][k + 2], x3 = h_s[b][k + 3];
        A0 = fmaf(w0.x, x0, A0); B0 = fmaf(w0.y, x1, B0); A0 = fmaf(w0.z, x2, A0); B0 = fmaf(w0.w, x3, B0);
        A1 = fmaf(w1.x, x0, A1); B1 = fmaf(w1.y, x1, B1); A1 = fmaf(w1.z, x2, A1); B1 = fmaf(w1.w, x3, B1);
        A2 = fmaf(w2.x, x0, A2); B2 = fmaf(w2.y, x1, B2); A2 = fmaf(w2.z, x2, A2); B2 = fmaf(w2.w, x3, B2);
        A3 = fmaf(w3.x, x0, A3); B3 = fmaf(w3.y, x1, B3); A3 = fmaf(w3.z, x2, A3); B3 = fmaf(w3.w, x3, B3);
    }

    float gi = A0 + B0, gf = A1 + B1, gg = A2 + B2, go = A3 + B3;
    float iv = 1.f / (1.f + expf(-gi));
    float fv = 1.f / (1.f + expf(-gf));
    float gv = tanhf(gg);
    float ov = 1.f / (1.f + expf(-go));

    const size_t off = (size_t)b * HIDDEN + j;
    float cn = fv * c_buf[off] + iv * gv;
    c_buf[off] = cn;
    float hv = ov * tanhf(cn);
    h_next[off] = hv;
    unsigned short hh = f2bf(hv);
    h_hi[off] = hh;
    h_lo[off] = f2bf(hv - bf2f(hh));
}

// ---------------- Kernel B (MFMA): logits GEMM + store + argmax ----------------
// grid 250 x 256 threads (4 waves). wave w: v in [blk*128 + w*32, +32), all 32 b.
// mfma_f32_16x16x32_bf16: A lane: m=lane&15, k=(lane>>4)*8+i ; B lane: n=lane&15, same k.
// D: col(n)=lane&15, row(m)=(lane>>4)*4+reg.
#define MFMA(a, b, c) __builtin_amdgcn_mfma_f32_16x16x32_bf16((a), (b), (c), 0, 0, 0)

__device__ __forceinline__ void store_argmax(
    f32x4 a, f32x4 bias, int b, int v4, int t,
    float* __restrict__ out, unsigned long long* best)
{
    f32x4 st;
    #pragma unroll
    for (int j = 0; j < 4; ++j) st[j] = a[j] + bias[j];
    *(f32x4*)(out + ((size_t)b * MAXLEN + t) * VOCAB + v4) = st;
    #pragma unroll
    for (int j = 0; j < 4; ++j) {
        unsigned long long e = ((unsigned long long)f32_ordered_key(st[j]) << 32)
                             | (unsigned long long)(~(unsigned int)(v4 + j));
        if (e > *best) *best = e;
    }
}

__global__ __launch_bounds__(256) void logits_mfma_kernel(
    const unsigned short* __restrict__ Whi, const unsigned short* __restrict__ Wlo,
    const unsigned short* __restrict__ hhi, const unsigned short* __restrict__ hlo,
    const float* __restrict__ b_fc, float* __restrict__ out,
    unsigned long long* __restrict__ slots, int t)
{
    const int tid  = threadIdx.x;
    const int w    = tid >> 6;
    const int lane = tid & 63;
    const int row  = lane & 15;
    const int kg   = lane >> 4;
    const int vwave = blockIdx.x * 128 + w * 32;

    const size_t wrow0 = (size_t)(vwave + row) * HIDDEN;
    const size_t wrow1 = (size_t)(vwave + 16 + row) * HIDDEN;
    const size_t hrow0 = (size_t)row * HIDDEN;
    const size_t hrow1 = (size_t)(16 + row) * HIDDEN;
    const int kbase = kg * 8;

    f32x4 acc00 = {0.f,0.f,0.f,0.f}, acc01 = {0.f,0.f,0.f,0.f};
    f32x4 acc10 = {0.f,0.f,0.f,0.f}, acc11 = {0.f,0.f,0.f,0.f};

#define LOADF(Wh0,Wh1,Wl0,Wl1,Hh0,Hh1,Hl0,Hl1, KO) do {               \
        const int _ko = (KO) + kbase;                                  \
        Wh0 = *(const bf16x8*)(Whi + wrow0 + _ko);                     \
        Wh1 = *(const bf16x8*)(Whi + wrow1 + _ko);                     \
        Wl0 = *(const bf16x8*)(Wlo + wrow0 + _ko);                     \
        Wl1 = *(const bf16x8*)(Wlo + wrow1 + _ko);                     \
        Hh0 = *(const bf16x8*)(hhi + hrow0 + _ko);                     \
        Hh1 = *(const bf16x8*)(hhi + hrow1 + _ko);                     \
        Hl0 = *(const bf16x8*)(hlo + hrow0 + _ko);                     \
        Hl1 = *(const bf16x8*)(hlo + hrow1 + _ko);                     \
    } while (0)

#define MFMA16(Wh0,Wh1,Wl0,Wl1,Hh0,Hh1,Hl0,Hl1) do {                   \
        acc00 = MFMA(Wh0, Hh0, acc00); acc01 = MFMA(Wh0, Hh1, acc01);  \
        acc10 = MFMA(Wh1, Hh0, acc10); acc11 = MFMA(Wh1, Hh1, acc11);  \
        acc00 = MFMA(Wh0, Hl0, acc00); acc01 = MFMA(Wh0, Hl1, acc01);  \
        acc10 = MFMA(Wh1, Hl0, acc10); acc11 = MFMA(Wh1, Hl1, acc11);  \
        acc00 = MFMA(Wl0, Hh0, acc00); acc01 = MFMA(Wl0, Hh1, acc01);  \
        acc10 = MFMA(Wl1, Hh0, acc10); acc11 = MFMA(Wl1, Hh1, acc11);  \
        acc00 = MFMA(Wl0, Hl0, acc00); acc01 = MFMA(Wl0, Hl1, acc01);  \
        acc10 = MFMA(Wl1, Hl0, acc10); acc11 = MFMA(Wl1, Hl1, acc11);  \
    } while (0)

    bf16x8 aWh0, aWh1, aWl0, aWl1, aHh0, aHh1, aHl0, aHl1;
    bf16x8 bWh0, bWh1, bWl0, bWl1, bHh0, bHh1, bHl0, bHl1;

    LOADF(aWh0,aWh1,aWl0,aWl1,aHh0,aHh1,aHl0,aHl1, 0);
    #pragma unroll
    for (int k0 = 0; k0 < HIDDEN; k0 += 64) {
        LOADF(bWh0,bWh1,bWl0,bWl1,bHh0,bHh1,bHl0,bHl1, k0 + 32);
        MFMA16(aWh0,aWh1,aWl0,aWl1,aHh0,aHh1,aHl0,aHl1);
        if (k0 + 64 < HIDDEN)
            LOADF(aWh0,aWh1,aWl0,aWl1,aHh0,aHh1,aHl0,aHl1, k0 + 64);
        MFMA16(bWh0,bWh1,bWl0,bWl1,bHh0,bHh1,bHl0,bHl1);
    }

    // epilogue: bias + store + argmax
    unsigned long long best0 = 0ull, best1 = 0ull;   // b=row, b=row+16
    {
        const int v40 = vwave + kg * 4;
        f32x4 bias0 = *(const f32x4*)(b_fc + v40);
        store_argmax(acc00, bias0, row,      v40, t, out, &best0);
        store_argmax(acc01, bias0, row + 16, v40, t, out, &best1);
        const int v41 = vwave + 16 + kg * 4;
        f32x4 bias1 = *(const f32x4*)(b_fc + v41);
        store_argmax(acc10, bias1, row,      v41, t, out, &best0);
        store_argmax(acc11, bias1, row + 16, v41, t, out, &best1);
    }
    // reduce across the 4 lanes sharing the same (lane&15): xor 16, 32 flip kg bits
    #pragma unroll
    for (int s = 16; s <= 32; s <<= 1) {
        unsigned long long o0 = __shfl_xor(best0, s, 64);
        unsigned long long o1 = __shfl_xor(best1, s, 64);
        if (o0 > best0) best0 = o0;
        if (o1 > best1) best1 = o1;
    }
    __shared__ unsigned long long red[4][BATCH];
    if (kg == 0) { red[w][row] = best0; red[w][row + 16] = best1; }
    __syncthreads();
    if (tid < BATCH) {
        unsigned long long m = red[0][tid];
        #pragma unroll
        for (int ww = 1; ww < 4; ++ww) if (red[ww][tid] > m) m = red[ww][tid];
        atomicMax(&slots[(size_t)t * BATCH + tid], m);
    }
}

// ---------------- fallback fp32 logits kernel (if ws too small) ----------------
#define VBLK  128
#define KTILE 64
__global__ __launch_bounds__(256) void logits_kernel(
    const float* __restrict__ W_fc, const float* __restrict__ b_fc,
    const float* __restrict__ h, float* __restrict__ out,
    unsigned long long* __restrict__ slots, int t)
{
    __shared__ float W_s[VBLK][KTILE + 1];
    __shared__ float h_s[BATCH][KTILE + 1];

    const int tid   = threadIdx.x;
    const int vbase = blockIdx.x * VBLK;
    const int vq    = tid & 31;
    const int bq    = tid >> 5;
    const int b0    = bq * 4;

    float acc[4][4] = {{0.f}};
    for (int kt = 0; kt < HIDDEN / KTILE; ++kt) {
        const int kb = kt * KTILE;
        __syncthreads();
        for (int idx = tid; idx < VBLK * KTILE; idx += 256) {
            int r = idx >> 6, cc = idx & 63;
            W_s[r][cc] = W_fc[(size_t)(vbase + r) * HIDDEN + kb + cc];
        }
        for (int idx = tid; idx < BATCH * KTILE; idx += 256) {
            int r = idx >> 6, cc = idx & 63;
            h_s[r][cc] = h[(size_t)r * HIDDEN + kb + cc];
        }
        __syncthreads();
        #pragma unroll 8
        for (int c = 0; c < KTILE; ++c) {
            float hv[4], wv[4];
            #pragma unroll
            for (int jj = 0; jj < 4; ++jj) hv[jj] = h_s[b0 + jj][c];
            #pragma unroll
            for (int i = 0; i < 4; ++i)  wv[i] = W_s[vq + 32 * i][c];
            #pragma unroll
            for (int i = 0; i < 4; ++i)
                #pragma unroll
                for (int jj = 0; jj < 4; ++jj)
                    acc[i][jj] = fmaf(wv[i], hv[jj], acc[i][jj]);
        }
    }
    float bfc[4];
    #pragma unroll
    for (int i = 0; i < 4; ++i) bfc[i] = b_fc[vbase + vq + 32 * i];
    unsigned long long best[4] = {0ull, 0ull, 0ull, 0ull};
    #pragma unroll
    for (int i = 0; i < 4; ++i) {
        const int v = vbase + vq + 32 * i;
        #pragma unroll
        for (int jj = 0; jj < 4; ++jj) {
            float val = acc[i][jj] + bfc[i];
            out[((size_t)(b0 + jj) * MAXLEN + t) * VOCAB + v] = val;
            unsigned long long enc =
                ((unsigned long long)f32_ordered_key(val) << 32) |
                (unsigned long long)(~(unsigned int)v);
            if (enc > best[jj]) best[jj] = enc;
        }
    }
    #pragma unroll
    for (int jj = 0; jj < 4; ++jj) {
        unsigned long long m = best[jj];
        #pragma unroll
        for (int s = 16; s >= 1; s >>= 1) {
            unsigned long long o = __shfl_xor(m, s, 64);
            if (o > m) m = o;
        }
        if (vq == 0)
            atomicMax(&slots[(size_t)t * BATCH + b0 + jj], m);
    }
}

extern "C" void kernel_launch(void* const* d_in, const int* in_sizes, int n_in,
                              void* d_out, int out_size, void* d_ws, size_t ws_size,
                              hipStream_t stream) {
    const float* embed = (const float*)d_in[1];
    const float* W_ih  = (const float*)d_in[2];
    const float* W_hh  = (const float*)d_in[3];
    const float* b_ih  = (const float*)d_in[4];
    const float* b_hh  = (const float*)d_in[5];
    const float* W_fc  = (const float*)d_in[6];
    const float* b_fc  = (const float*)d_in[7];
    float* out = (float*)d_out;

    char* ws = (char*)d_ws;
    float* h_buf = (float*)(ws + WS_H_OFF);
    float* c_buf = (float*)(ws + WS_C_OFF);
    unsigned long long* slots = (unsigned long long*)(ws + WS_S_OFF);
    unsigned short* h_hi = (unsigned short*)(ws + WS_HHI_OFF);
    unsigned short* h_lo = (unsigned short*)(ws + WS_HLO_OFF);
    unsigned short* W_hi = (unsigned short*)(ws + WS_WHI_OFF);
    unsigned short* W_lo = (unsigned short*)(ws + WS_WLO_OFF);

    const bool use_mfma = (ws_size >= WS_REQUIRED);

    hipMemsetAsync(d_ws, 0, WS_ZERO_BYTES, stream);
    if (use_mfma) {
        split_w_kernel<<<2048, 256, 0, stream>>>(W_fc, W_hi, W_lo, VOCAB * HIDDEN / 4);
    }

    for (int t = 0; t < MAXLEN; ++t) {
        float* h_prev = h_buf + (size_t)(t & 1) * BATCH * HIDDEN;
        float* h_next = h_buf + (size_t)((t + 1) & 1) * BATCH * HIDDEN;
        lstm_step_kernel<<<64, 256, 0, stream>>>(
            embed, W_ih, W_hh, b_ih, b_hh, slots, h_prev, h_next, c_buf, h_hi, h_lo, t);
        if (use_mfma) {
            logits_mfma_kernel<<<VOCAB / 128, 256, 0, stream>>>(
                W_hi, W_lo, h_hi, h_lo, b_fc, out, slots, t);
        } else {
            logits_kernel<<<VOCAB / VBLK, 256, 0, stream>>>(
                W_fc, b_fc, h_next, out, slots, t);
        }
    }
}

// Round 3
// 4647.530 us; speedup vs baseline: 2.9447x; 1.7450x over previous
//
#include <hip/hip_runtime.h>
#include <hip/hip_bf16.h>
#include <math.h>

#define VOCAB  32000
#define EMBED  256
#define HIDDEN 512
#define BATCH  32
#define MAXLEN 128
#define NCAND  250            // logits blocks = argmax candidates per b

typedef __attribute__((ext_vector_type(8))) short bf16x8;          // 8 bf16 = 4 VGPR
typedef __attribute__((ext_vector_type(8))) unsigned short ushort8;
typedef __attribute__((ext_vector_type(4))) float f32x4;

// -------- workspace layout (bytes) --------
#define WS_C_OFF     0          // c[32][512] f32                    65536
#define WS_HHI_OFF   65536      // h_hi[2][32][512] bf16             65536
#define WS_HLO_OFF   131072     // h_lo[2][32][512] bf16             65536
#define WS_CAND_OFF  196608     // cand[250][32] u64                 64000
#define WS_WHI_OFF   260608     // W_hi[32000][512] bf16          32768000
#define WS_WLO_OFF   33028608   // W_lo[32000][512] bf16          32768000
#define WS_ZERO_BYTES 196608    // c + both h parities must start 0

__device__ __forceinline__ unsigned int f32_ordered_key(float f) {
    unsigned int b = __float_as_uint(f);
    return (b & 0x80000000u) ? ~b : (b | 0x80000000u);
}
__device__ __forceinline__ unsigned short f2bf(float x) {
    __hip_bfloat16 h = __float2bfloat16(x);
    return *reinterpret_cast<unsigned short*>(&h);
}
__device__ __forceinline__ float bf2f(unsigned short u) {
    __hip_bfloat16 h = *reinterpret_cast<__hip_bfloat16*>(&u);
    return __bfloat162float(h);
}

// ---------------- W_fc bf16 split precompute (once per launch) ----------------
__global__ __launch_bounds__(256) void split_w_kernel(
    const float* __restrict__ W, unsigned short* __restrict__ hi,
    unsigned short* __restrict__ lo, int n4)
{
    const int stride = gridDim.x * blockDim.x;
    for (int i = blockIdx.x * blockDim.x + threadIdx.x; i < n4; i += stride) {
        f32x4 w = ((const f32x4*)W)[i];
        ushort4 hv, lv;
        #pragma unroll
        for (int j = 0; j < 4; ++j) {
            float x = w[j];
            unsigned short hb = f2bf(x);
            ((unsigned short*)&hv)[j] = hb;
            ((unsigned short*)&lv)[j] = f2bf(x - bf2f(hb));
        }
        ((ushort4*)hi)[i] = hv;
        ((ushort4*)lo)[i] = lv;
    }
}

// ---------------- Kernel A: argmax-reduce + gather + gates + LSTM cell ----------------
// grid 256 x 256 threads. block handles j = blk*2 + {0,1} (all 4 gates, all 32 b).
// thread (b = tid&31, s = (tid>>5)&3 [k-quarter], jp = tid>>7).
__global__ __launch_bounds__(256) void lstm_step_kernel(
    const float* __restrict__ embed,
    const float* __restrict__ W_ih, const float* __restrict__ W_hh,
    const float* __restrict__ b_ih, const float* __restrict__ b_hh,
    const unsigned long long* __restrict__ cand,
    const unsigned short* __restrict__ hhi_prev, const unsigned short* __restrict__ hlo_prev,
    unsigned short* __restrict__ hhi_next, unsigned short* __restrict__ hlo_next,
    float* __restrict__ c_buf, int t)
{
    __shared__ float x_t[EMBED][33];    // transposed, padded: x_t[e][b]
    __shared__ float h_t[HIDDEN][33];   // transposed, padded: h_t[k][b]
    __shared__ int   tok_s[BATCH];
    __shared__ unsigned long long credl[8][BATCH];
    __shared__ float part[2][4][BATCH][4];   // [jp][s][b][gate]
    __shared__ float gate_s[2][4][BATCH];    // [jp][gate][b]

    const int tid = threadIdx.x;

    // ---- argmax reduce over 250 candidates per batch row ----
    if (t > 0) {
        const int rb = tid & 31, seg = tid >> 5;
        unsigned long long m = 0ull;
        for (int i = seg; i < NCAND; i += 8) {
            unsigned long long e = cand[(size_t)i * BATCH + rb];
            if (e > m) m = e;
        }
        credl[seg][rb] = m;
        __syncthreads();
        if (tid < BATCH) {
            unsigned long long mm = credl[0][tid];
            #pragma unroll
            for (int ss = 1; ss < 8; ++ss) if (credl[ss][tid] > mm) mm = credl[ss][tid];
            tok_s[tid] = (int)(~(unsigned int)(mm & 0xFFFFFFFFull));
        }
    } else {
        if (tid < BATCH) tok_s[tid] = 0;
    }
    __syncthreads();

    // ---- stage x (gather) and h (reconstruct hi+lo) transposed into LDS ----
    {
        const int sb = tid >> 3, slot = tid & 7;
        const float* er = embed + (size_t)tok_s[sb] * EMBED;
        #pragma unroll
        for (int i = 0; i < 8; ++i) {
            int e4 = i * 8 + slot;
            float4 v = ((const float4*)er)[e4];
            int e = e4 * 4;
            x_t[e + 0][sb] = v.x; x_t[e + 1][sb] = v.y;
            x_t[e + 2][sb] = v.z; x_t[e + 3][sb] = v.w;
        }
        const ushort8* hr = (const ushort8*)(hhi_prev + (size_t)sb * HIDDEN);
        const ushort8* lr = (const ushort8*)(hlo_prev + (size_t)sb * HIDDEN);
        #pragma unroll
        for (int i = 0; i < 8; ++i) {
            int u = i * 8 + slot;
            ushort8 hv = hr[u], lv = lr[u];
            #pragma unroll
            for (int e = 0; e < 8; ++e)
                h_t[u * 8 + e][sb] = bf2f((unsigned short)hv[e]) + bf2f((unsigned short)lv[e]);
        }
    }
    __syncthreads();

    // ---- gates partial dot products ----
    const int b  = tid & 31;
    const int s  = (tid >> 5) & 3;
    const int jp = tid >> 7;
    const int j  = blockIdx.x * 2 + jp;

    float a0 = 0.f, a1 = 0.f, a2 = 0.f, a3 = 0.f;
    float d0 = 0.f, d1 = 0.f, d2 = 0.f, d3 = 0.f;

    {   // x part: e in [s*64, s*64+64)
        const float4* w0 = (const float4*)(W_ih + (size_t)j * EMBED) + s * 16;
        const float4* w1 = (const float4*)(W_ih + (size_t)(HIDDEN + j) * EMBED) + s * 16;
        const float4* w2 = (const float4*)(W_ih + (size_t)(2 * HIDDEN + j) * EMBED) + s * 16;
        const float4* w3 = (const float4*)(W_ih + (size_t)(3 * HIDDEN + j) * EMBED) + s * 16;
        #pragma unroll 4
        for (int g = 0; g < 16; ++g) {
            float4 W0 = w0[g], W1 = w1[g], W2 = w2[g], W3 = w3[g];
            int e = s * 64 + g * 4;
            float x0 = x_t[e + 0][b], x1 = x_t[e + 1][b], x2 = x_t[e + 2][b], x3 = x_t[e + 3][b];
            a0 = fmaf(W0.x, x0, a0); d0 = fmaf(W0.y, x1, d0); a0 = fmaf(W0.z, x2, a0); d0 = fmaf(W0.w, x3, d0);
            a1 = fmaf(W1.x, x0, a1); d1 = fmaf(W1.y, x1, d1); a1 = fmaf(W1.z, x2, a1); d1 = fmaf(W1.w, x3, d1);
            a2 = fmaf(W2.x, x0, a2); d2 = fmaf(W2.y, x1, d2); a2 = fmaf(W2.z, x2, a2); d2 = fmaf(W2.w, x3, d2);
            a3 = fmaf(W3.x, x0, a3); d3 = fmaf(W3.y, x1, d3); a3 = fmaf(W3.z, x2, a3); d3 = fmaf(W3.w, x3, d3);
        }
    }
    {   // h part: k in [s*128, s*128+128)
        const float4* w0 = (const float4*)(W_hh + (size_t)j * HIDDEN) + s * 32;
        const float4* w1 = (const float4*)(W_hh + (size_t)(HIDDEN + j) * HIDDEN) + s * 32;
        const float4* w2 = (const float4*)(W_hh + (size_t)(2 * HIDDEN + j) * HIDDEN) + s * 32;
        const float4* w3 = (const float4*)(W_hh + (size_t)(3 * HIDDEN + j) * HIDDEN) + s * 32;
        #pragma unroll 4
        for (int g = 0; g < 32; ++g) {
            float4 W0 = w0[g], W1 = w1[g], W2 = w2[g], W3 = w3[g];
            int k = s * 128 + g * 4;
            float x0 = h_t[k + 0][b], x1 = h_t[k + 1][b], x2 = h_t[k + 2][b], x3 = h_t[k + 3][b];
            a0 = fmaf(W0.x, x0, a0); d0 = fmaf(W0.y, x1, d0); a0 = fmaf(W0.z, x2, a0); d0 = fmaf(W0.w, x3, d0);
            a1 = fmaf(W1.x, x0, a1); d1 = fmaf(W1.y, x1, d1); a1 = fmaf(W1.z, x2, a1); d1 = fmaf(W1.w, x3, d1);
            a2 = fmaf(W2.x, x0, a2); d2 = fmaf(W2.y, x1, d2); a2 = fmaf(W2.z, x2, a2); d2 = fmaf(W2.w, x3, d2);
            a3 = fmaf(W3.x, x0, a3); d3 = fmaf(W3.y, x1, d3); a3 = fmaf(W3.z, x2, a3); d3 = fmaf(W3.w, x3, d3);
        }
    }
    part[jp][s][b][0] = a0 + d0;
    part[jp][s][b][1] = a1 + d1;
    part[jp][s][b][2] = a2 + d2;
    part[jp][s][b][3] = a3 + d3;
    __syncthreads();

    // ---- gate reduce + nonlinearity (256 threads = 2j x 4gate x 32b) ----
    {
        const int gb = tid & 31, gate = (tid >> 5) & 3, gjp = tid >> 7;
        const int jj = blockIdx.x * 2 + gjp;
        float g = part[gjp][0][gb][gate] + part[gjp][1][gb][gate]
                + part[gjp][2][gb][gate] + part[gjp][3][gb][gate];
        g += b_ih[gate * HIDDEN + jj] + b_hh[gate * HIDDEN + jj];
        gate_s[gjp][gate][gb] = (gate == 2) ? tanhf(g) : 1.f / (1.f + expf(-g));
    }
    __syncthreads();

    // ---- cell update (64 threads) ----
    if (tid < 64) {
        const int cb = tid & 31, cjp = tid >> 5;
        const int jj = blockIdx.x * 2 + cjp;
        const float iv = gate_s[cjp][0][cb], fv = gate_s[cjp][1][cb];
        const float gv = gate_s[cjp][2][cb], ov = gate_s[cjp][3][cb];
        const size_t off = (size_t)cb * HIDDEN + jj;
        float cn = fv * c_buf[off] + iv * gv;
        c_buf[off] = cn;
        float hv = ov * tanhf(cn);
        unsigned short hh = f2bf(hv);
        hhi_next[off] = hh;
        hlo_next[off] = f2bf(hv - bf2f(hh));
    }
}

// ---------------- Kernel B (MFMA): logits GEMM + store + per-block argmax ----------------
// grid 250 x 512 threads (8 waves). wave w: 16 v-rows x 32 b. h hi/lo staged in swizzled LDS.
// 3-pass split: Wh*Hh + Wl*Hh + Wh*Hl (lo*lo dropped, ~1e-7 contribution).
#define MFMA(a, b, c) __builtin_amdgcn_mfma_f32_16x16x32_bf16((a), (b), (c), 0, 0, 0)
#define HPTR(arr, bb, cc) \
    ((const bf16x8*)((const char*)(arr) + ((((bb) * 1024) + (kg * 16) + (cc) * 64) ^ ((((bb) & 7)) << 4))))

__global__ __launch_bounds__(512) void logits_mfma_kernel(
    const unsigned short* __restrict__ Whi, const unsigned short* __restrict__ Wlo,
    const unsigned short* __restrict__ hhi, const unsigned short* __restrict__ hlo,
    const float* __restrict__ b_fc, float* __restrict__ out,
    unsigned long long* __restrict__ cand, int t)
{
    __shared__ unsigned short hs_hi[BATCH * HIDDEN];   // 32KB, XOR-swizzled rows
    __shared__ unsigned short hs_lo[BATCH * HIDDEN];   // 32KB
    __shared__ unsigned long long red[8][BATCH];

    const int tid = threadIdx.x;

    // ---- stage h hi/lo into swizzled LDS (4096 16B units / 512 threads = 8 each) ----
    #pragma unroll
    for (int i = 0; i < 8; ++i) {
        int u   = i * 512 + tid;
        int arr = u >> 11;               // 0 = hi, 1 = lo
        int b   = (u >> 6) & 31;
        int k16 = u & 63;
        const unsigned short* src = (arr ? hlo : hhi) + (size_t)b * HIDDEN + k16 * 8;
        int4 v = *(const int4*)src;
        char* dst = (char*)(arr ? hs_lo : hs_hi) + ((b * 1024 + k16 * 16) ^ ((b & 7) << 4));
        *(int4*)dst = v;
    }
    __syncthreads();

    const int w    = tid >> 6;
    const int lane = tid & 63;
    const int row  = lane & 15;          // v-row within tile (A), also b for acc0 (B)
    const int kg   = lane >> 4;
    const int vwave = blockIdx.x * 128 + w * 16;

    const unsigned short* wh = Whi + (size_t)(vwave + row) * HIDDEN + kg * 8;
    const unsigned short* wl = Wlo + (size_t)(vwave + row) * HIDDEN + kg * 8;

    f32x4 acc0 = {0.f, 0.f, 0.f, 0.f};   // b = row
    f32x4 acc1 = {0.f, 0.f, 0.f, 0.f};   // b = row + 16

    bf16x8 awh = *(const bf16x8*)(wh);
    bf16x8 awl = *(const bf16x8*)(wl);
    #pragma unroll
    for (int c = 0; c < 15; ++c) {
        bf16x8 nwh = *(const bf16x8*)(wh + (c + 1) * 32);
        bf16x8 nwl = *(const bf16x8*)(wl + (c + 1) * 32);
        bf16x8 hh0 = *HPTR(hs_hi, row, c),      hh1 = *HPTR(hs_hi, row + 16, c);
        bf16x8 hl0 = *HPTR(hs_lo, row, c),      hl1 = *HPTR(hs_lo, row + 16, c);
        acc0 = MFMA(awh, hh0, acc0); acc1 = MFMA(awh, hh1, acc1);
        acc0 = MFMA(awl, hh0, acc0); acc1 = MFMA(awl, hh1, acc1);
        acc0 = MFMA(awh, hl0, acc0); acc1 = MFMA(awh, hl1, acc1);
        awh = nwh; awl = nwl;
    }
    {
        const int c = 15;
        bf16x8 hh0 = *HPTR(hs_hi, row, c),      hh1 = *HPTR(hs_hi, row + 16, c);
        bf16x8 hl0 = *HPTR(hs_lo, row, c),      hl1 = *HPTR(hs_lo, row + 16, c);
        acc0 = MFMA(awh, hh0, acc0); acc1 = MFMA(awh, hh1, acc1);
        acc0 = MFMA(awl, hh0, acc0); acc1 = MFMA(awl, hh1, acc1);
        acc0 = MFMA(awh, hl0, acc0); acc1 = MFMA(awh, hl1, acc1);
    }

    // ---- epilogue: bias + store + argmax candidates ----
    const int v4 = vwave + kg * 4;        // D: row(m) = kg*4 + reg -> v; col(n) = row -> b
    f32x4 bias = *(const f32x4*)(b_fc + v4);
    f32x4 st0, st1;
    unsigned long long best0 = 0ull, best1 = 0ull;
    #pragma unroll
    for (int jj = 0; jj < 4; ++jj) {
        st0[jj] = acc0[jj] + bias[jj];
        st1[jj] = acc1[jj] + bias[jj];
        unsigned long long e0 = ((unsigned long long)f32_ordered_key(st0[jj]) << 32)
                              | (unsigned long long)(~(unsigned int)(v4 + jj));
        unsigned long long e1 = ((unsigned long long)f32_ordered_key(st1[jj]) << 32)
                              | (unsigned long long)(~(unsigned int)(v4 + jj));
        if (e0 > best0) best0 = e0;
        if (e1 > best1) best1 = e1;
    }
    *(f32x4*)(out + ((size_t)row * MAXLEN + t) * VOCAB + v4)        = st0;
    *(f32x4*)(out + ((size_t)(row + 16) * MAXLEN + t) * VOCAB + v4) = st1;

    #pragma unroll
    for (int sft = 16; sft <= 32; sft <<= 1) {
        unsigned long long o0 = __shfl_xor(best0, sft, 64);
        unsigned long long o1 = __shfl_xor(best1, sft, 64);
        if (o0 > best0) best0 = o0;
        if (o1 > best1) best1 = o1;
    }
    if (kg == 0) { red[w][row] = best0; red[w][row + 16] = best1; }
    __syncthreads();
    if (tid < BATCH) {
        unsigned long long m = red[0][tid];
        #pragma unroll
        for (int ww = 1; ww < 8; ++ww) if (red[ww][tid] > m) m = red[ww][tid];
        cand[(size_t)blockIdx.x * BATCH + tid] = m;   // plain store, no atomics
    }
}

extern "C" void kernel_launch(void* const* d_in, const int* in_sizes, int n_in,
                              void* d_out, int out_size, void* d_ws, size_t ws_size,
                              hipStream_t stream) {
    const float* embed = (const float*)d_in[1];
    const float* W_ih  = (const float*)d_in[2];
    const float* W_hh  = (const float*)d_in[3];
    const float* b_ih  = (const float*)d_in[4];
    const float* b_hh  = (const float*)d_in[5];
    const float* W_fc  = (const float*)d_in[6];
    const float* b_fc  = (const float*)d_in[7];
    float* out = (float*)d_out;

    char* ws = (char*)d_ws;
    float* c_buf = (float*)(ws + WS_C_OFF);
    unsigned short* h_hi = (unsigned short*)(ws + WS_HHI_OFF);   // [2][32][512]
    unsigned short* h_lo = (unsigned short*)(ws + WS_HLO_OFF);   // [2][32][512]
    unsigned long long* cand = (unsigned long long*)(ws + WS_CAND_OFF);
    unsigned short* W_hi = (unsigned short*)(ws + WS_WHI_OFF);
    unsigned short* W_lo = (unsigned short*)(ws + WS_WLO_OFF);

    hipMemsetAsync(d_ws, 0, WS_ZERO_BYTES, stream);
    split_w_kernel<<<2048, 256, 0, stream>>>(W_fc, W_hi, W_lo, VOCAB * HIDDEN / 4);

    for (int t = 0; t < MAXLEN; ++t) {
        const int p = t & 1;
        unsigned short* hhi_prev = h_hi + (size_t)p * BATCH * HIDDEN;
        unsigned short* hlo_prev = h_lo + (size_t)p * BATCH * HIDDEN;
        unsigned short* hhi_next = h_hi + (size_t)(p ^ 1) * BATCH * HIDDEN;
        unsigned short* hlo_next = h_lo + (size_t)(p ^ 1) * BATCH * HIDDEN;
        lstm_step_kernel<<<256, 256, 0, stream>>>(
            embed, W_ih, W_hh, b_ih, b_hh, cand,
            hhi_prev, hlo_prev, hhi_next, hlo_next, c_buf, t);
        logits_mfma_kernel<<<NCAND, 512, 0, stream>>>(
            W_hi, W_lo, hhi_next, hlo_next, b_fc, out, cand, t);
    }
}